// Round 2
// baseline (733.438 us; speedup 1.0000x reference)
//
#include <hip/hip_runtime.h>

typedef unsigned short u16;
typedef unsigned int u32;

#define B_ 4
#define N_ 256
#define T_ 36
#define C_ 64
#define H_ 4
#define D_ 16
#define CH_ 128
#define E_ 4096
#define G_ (B_*T_)
#define TOK_ (B_*N_*T_)

// workspace layout (float offsets)
#define DS_OFF  0
#define O_OFF   (DS_OFF + N_*C_)
#define XG_OFF  (O_OFF + TOK_*C_)
#define INT_OFF (XG_OFF + TOK_*C_)

__device__ __forceinline__ float bf2f(u16 u){
  u32 x = ((u32)u) << 16;
  return __builtin_bit_cast(float, x);
}
__device__ __forceinline__ u16 f2bf(float f){
  u32 x = __builtin_bit_cast(u32, f);
  x += 0x7fffu + ((x >> 16) & 1u);
  return (u16)(x >> 16);
}
__device__ __forceinline__ void unpack8(uint4 u, float* f){
  f[0]=bf2f((u16)(u.x & 0xffffu)); f[1]=bf2f((u16)(u.x >> 16));
  f[2]=bf2f((u16)(u.y & 0xffffu)); f[3]=bf2f((u16)(u.y >> 16));
  f[4]=bf2f((u16)(u.z & 0xffffu)); f[5]=bf2f((u16)(u.z >> 16));
  f[6]=bf2f((u16)(u.w & 0xffffu)); f[7]=bf2f((u16)(u.w >> 16));
}
__device__ __forceinline__ uint4 pack8f(const float* f){
  uint4 u;
  u.x = (u32)f2bf(f[0]) | ((u32)f2bf(f[1]) << 16);
  u.y = (u32)f2bf(f[2]) | ((u32)f2bf(f[3]) << 16);
  u.z = (u32)f2bf(f[4]) | ((u32)f2bf(f[5]) << 16);
  u.w = (u32)f2bf(f[6]) | ((u32)f2bf(f[7]) << 16);
  return u;
}
__device__ __forceinline__ float wsum64(float v){
  #pragma unroll
  for (int m = 32; m > 0; m >>= 1) v += __shfl_xor(v, m, 64);
  return v;
}

// ---------------- deterministic CSR: bucket by dst (atomic), stable-sort by edge id ----------------
__global__ void k_csr(const int* __restrict__ ei, int* __restrict__ indptr, int* __restrict__ srcs)
{
  __shared__ int srcL[E_];
  __shared__ int dstL[E_];
  __shared__ int tmp[E_];
  __shared__ int cnt[N_];
  __shared__ int base[N_+1];
  const int tid = threadIdx.x;   // 256
  for (int e = tid; e < E_; e += 256){ srcL[e] = ei[e]; dstL[e] = ei[E_ + e]; }
  cnt[tid] = 0;
  __syncthreads();
  for (int e = tid; e < E_; e += 256) atomicAdd(&cnt[dstL[e]], 1);
  __syncthreads();
  if (tid == 0){
    int run = 0;
    for (int i = 0; i < N_; i++){ base[i] = run; run += cnt[i]; }
    base[N_] = run;
  }
  __syncthreads();
  cnt[tid] = 0;
  __syncthreads();
  for (int e = tid; e < E_; e += 256){
    int d = dstL[e];
    int p = atomicAdd(&cnt[d], 1);
    tmp[base[d] + p] = e;                   // unstable order
  }
  __syncthreads();
  {
    const int p0 = base[tid], p1 = base[tid] + cnt[tid];
    for (int i = p0 + 1; i < p1; i++){      // insertion sort by edge id -> stable/deterministic
      int v = tmp[i]; int j = i - 1;
      while (j >= p0 && tmp[j] > v){ tmp[j+1] = tmp[j]; j--; }
      tmp[j+1] = v;
    }
    for (int j = p0; j < p1; j++) srcs[j] = srcL[tmp[j]];
  }
  indptr[tid] = base[tid];
  if (tid == 0) indptr[N_] = base[N_];
}

// ---------------- ds = D_S @ W_emb + b_emb ----------------
__global__ void k_ds(const float* __restrict__ DSm, const float* __restrict__ Wemb,
                     const float* __restrict__ bemb, float* __restrict__ dsb)
{
  const int n = blockIdx.x, c = threadIdx.x;
  float acc = bemb[c];
  for (int m = 0; m < N_; m++) acc += DSm[n*N_ + m] * Wemb[m*C_ + c];
  dsb[n*C_ + c] = acc;
}

// ---------------- edge softmax helper (per-dst) ----------------
__device__ __forceinline__ void edge_softmax(int nid, const int* __restrict__ indptr,
                                             const int* __restrict__ srcs,
                                             const float* hsv, float hdn, float* alpha)
{
  const int p0 = indptr[nid], p1 = indptr[nid+1];
  float m = -1e30f;
  for (int j = p0; j < p1; j++){
    float e = hsv[srcs[j]] + hdn;
    e = e > 0.f ? e : 0.2f * e;
    alpha[j] = e;
    m = fmaxf(m, e);
  }
  float s = 0.f;
  for (int j = p0; j < p1; j++){
    float w = __expf(alpha[j] - m);
    alpha[j] = w; s += w;
  }
  float inv = 1.f / (s + 1e-16f);
  for (int j = p0; j < p1; j++) alpha[j] *= inv;
}

// ---------------- GAT: one block per (b,t) graph ----------------
#define XP_ 68    // f32 x stride (rows 272B: 16B-aligned, stride%32==4 words -> b128 conflict-free)
#define HP_ 136   // u16 h stride (rows 272B: same property for uint4 (8xbf16) access)
__global__ __launch_bounds__(512, 2)
void k_gat(const float* __restrict__ query,
           const float* __restrict__ W1, const float* __restrict__ as1, const float* __restrict__ ad1, const float* __restrict__ b1,
           const float* __restrict__ W2, const float* __restrict__ as2, const float* __restrict__ ad2, const float* __restrict__ b2,
           const float* __restrict__ jkW, const float* __restrict__ jkb,
           const int* __restrict__ indptr, const int* __restrict__ srcs,
           float* __restrict__ xg)
{
  __shared__ union UU {
    float xs[N_][XP_];      // staged input x (f32)
    u16   h1[N_][HP_];      // then: h1 = relu(agg1+b1); then: max(h1,h2) (jk input)
  } U;
  __shared__ u16 hA[N_][HP_];   // conv output h (bf16), per layer
  __shared__ float alpha[E_];
  __shared__ float hsv[N_];
  __shared__ float hdv[N_];

  const int g = blockIdx.x;
  const int b = g / T_, tg = g % T_;
  const int tid = threadIdx.x;
  const int n = tid & (N_-1);
  const int half = tid >> 8;       // wave-uniform
  const int c0 = half * 64;

  // stage x rows (f32) into U.xs, coalesced float4
  {
    const size_t gb = (((size_t)b * N_) * T_ + tg) * C_;
    #pragma unroll
    for (int it = 0; it < 8; it++){
      int u = tid + 512*it;                 // 0..4095
      int row = u >> 4, c4 = (u & 15) * 4;
      *(float4*)&U.xs[row][c4] = *(const float4*)(query + gb + (size_t)row * (T_*C_) + c4);
    }
  }
  __syncthreads();

  // conv1 linear: hA = bf16(x @ W1)   (thread: node n, cols [c0,c0+64))
  for (int cc = 0; cc < 64; cc += 32){
    float acc[32];
    #pragma unroll
    for (int j = 0; j < 32; j++) acc[j] = 0.f;
    for (int k = 0; k < 64; k += 4){
      float4 xv = *(const float4*)&U.xs[n][k];
      float xa[4] = {xv.x, xv.y, xv.z, xv.w};
      #pragma unroll
      for (int kk = 0; kk < 4; kk++){
        const float* wrow = W1 + (k+kk)*CH_ + c0 + cc;   // wave-uniform -> scalar loads
        #pragma unroll
        for (int j = 0; j < 32; j++) acc[j] += xa[kk] * wrow[j];
      }
    }
    #pragma unroll
    for (int j8 = 0; j8 < 32; j8 += 8)
      *(uint4*)&hA[n][c0+cc+j8] = pack8f(&acc[j8]);
  }
  __syncthreads();

  // hs/hd for conv1
  if (tid < N_){
    float hs = 0.f, hd = 0.f;
    for (int k8 = 0; k8 < 16; k8++){
      uint4 hu = *(const uint4*)&hA[tid][k8*8];
      float hv[8]; unpack8(hu, hv);
      #pragma unroll
      for (int kk = 0; kk < 8; kk++){
        int k = k8*8 + kk;
        hs += hv[kk] * as1[k];
        hd += hv[kk] * ad1[k];
      }
    }
    hsv[tid] = hs; hdv[tid] = hd;
  }
  __syncthreads();
  if (tid < N_) edge_softmax(tid, indptr, srcs, hsv, hdv[tid], alpha);
  __syncthreads();

  // aggregation 1 -> U.h1 = bf16(relu(agg + b1))   (x in U is dead)
  {
    const int p0 = indptr[n], p1 = indptr[n+1];
    for (int cc = c0; cc < c0 + 64; cc += 8){
      float acc[8];
      #pragma unroll
      for (int i = 0; i < 8; i++) acc[i] = 0.f;
      for (int j = p0; j < p1; j++){
        float a = alpha[j];
        int s = srcs[j];
        uint4 hu = *(const uint4*)&hA[s][cc];
        float hv[8]; unpack8(hu, hv);
        #pragma unroll
        for (int i = 0; i < 8; i++) acc[i] += a * hv[i];
      }
      float o[8];
      #pragma unroll
      for (int i = 0; i < 8; i++){
        float v = acc[i] + b1[cc+i];
        o[i] = v > 0.f ? v : 0.f;
      }
      *(uint4*)&U.h1[n][cc] = pack8f(o);
    }
  }
  __syncthreads();

  // conv2 linear: hA = bf16(h1 @ W2)
  for (int cc = 0; cc < 64; cc += 32){
    float acc[32];
    #pragma unroll
    for (int j = 0; j < 32; j++) acc[j] = 0.f;
    for (int k8 = 0; k8 < 16; k8++){
      uint4 hu = *(const uint4*)&U.h1[n][k8*8];
      float hv[8]; unpack8(hu, hv);
      #pragma unroll
      for (int kk = 0; kk < 8; kk++){
        const float* wrow = W2 + (k8*8+kk)*CH_ + c0 + cc;
        #pragma unroll
        for (int j = 0; j < 32; j++) acc[j] += hv[kk] * wrow[j];
      }
    }
    #pragma unroll
    for (int j8 = 0; j8 < 32; j8 += 8)
      *(uint4*)&hA[n][c0+cc+j8] = pack8f(&acc[j8]);
  }
  __syncthreads();

  // hs/hd for conv2
  if (tid < N_){
    float hs = 0.f, hd = 0.f;
    for (int k8 = 0; k8 < 16; k8++){
      uint4 hu = *(const uint4*)&hA[tid][k8*8];
      float hv[8]; unpack8(hu, hv);
      #pragma unroll
      for (int kk = 0; kk < 8; kk++){
        int k = k8*8 + kk;
        hs += hv[kk] * as2[k];
        hd += hv[kk] * ad2[k];
      }
    }
    hsv[tid] = hs; hdv[tid] = hd;
  }
  __syncthreads();
  if (tid < N_) edge_softmax(tid, indptr, srcs, hsv, hdv[tid], alpha);
  __syncthreads();

  // aggregation 2; U.h1 = max(h1, relu(agg2 + b2))   (jk 'max', in place)
  {
    const int p0 = indptr[n], p1 = indptr[n+1];
    for (int cc = c0; cc < c0 + 64; cc += 8){
      float acc[8];
      #pragma unroll
      for (int i = 0; i < 8; i++) acc[i] = 0.f;
      for (int j = p0; j < p1; j++){
        float a = alpha[j];
        int s = srcs[j];
        uint4 hu = *(const uint4*)&hA[s][cc];
        float hv[8]; unpack8(hu, hv);
        #pragma unroll
        for (int i = 0; i < 8; i++) acc[i] += a * hv[i];
      }
      uint4 h1u = *(const uint4*)&U.h1[n][cc];
      float h1v[8]; unpack8(h1u, h1v);
      float o[8];
      #pragma unroll
      for (int i = 0; i < 8; i++){
        float v = acc[i] + b2[cc+i];
        v = v > 0.f ? v : 0.f;
        o[i] = fmaxf(h1v[i], v);
      }
      *(uint4*)&U.h1[n][cc] = pack8f(o);
    }
  }
  __syncthreads();

  // jk linear: xg(time-reversed) = max(h1,h2) @ jk_W + jk_b
  {
    const int co0 = half * 32;
    float acc[32];
    #pragma unroll
    for (int j = 0; j < 32; j++) acc[j] = 0.f;
    for (int k8 = 0; k8 < 16; k8++){
      uint4 hu = *(const uint4*)&U.h1[n][k8*8];
      float hv[8]; unpack8(hu, hv);
      #pragma unroll
      for (int kk = 0; kk < 8; kk++){
        const float* wrow = jkW + (k8*8+kk)*C_ + co0;
        #pragma unroll
        for (int j = 0; j < 32; j++) acc[j] += hv[kk] * wrow[j];
      }
    }
    float* op = xg + ((((size_t)b*N_ + n)*T_) + (T_-1-tg))*C_ + co0;
    #pragma unroll
    for (int j4 = 0; j4 < 32; j4 += 4){
      float4 v = make_float4(acc[j4] + jkb[co0+j4], acc[j4+1] + jkb[co0+j4+1],
                             acc[j4+2] + jkb[co0+j4+2], acc[j4+3] + jkb[co0+j4+3]);
      *(float4*)(op + j4) = v;
    }
  }
}

// ---------------- attention: one block per (b,t,h); softmax over the q axis ----------------
#define QP_ 20
__global__ __launch_bounds__(256, 2)
void k_attn(const float* __restrict__ query, const float* __restrict__ key, const float* __restrict__ value,
            const float* __restrict__ Wq, const float* __restrict__ Wk, const float* __restrict__ Wv,
            const float* __restrict__ dsb, float* __restrict__ o_ws)
{
  __shared__ float qh[N_][QP_];
  __shared__ float kh[N_][QP_];
  __shared__ float vh[N_][QP_];
  __shared__ float mArr[N_];
  __shared__ float invArr[N_];
  __shared__ float wq[16][16], wk[16][16], wv[16][16];

  const int bx = blockIdx.x;
  const int b = bx / (T_*H_);
  const int r = bx % (T_*H_);
  const int t = r / H_;
  const int h = r % H_;
  const int n = threadIdx.x;

  wq[n >> 4][n & 15] = Wq[n];
  wk[n >> 4][n & 15] = Wk[n];
  wv[n >> 4][n & 15] = Wv[n];

  const size_t base = ((((size_t)b*N_ + n)*T_) + t)*C_ + h*D_;
  float qv[16], kv[16], vv[16];
  #pragma unroll
  for (int j4 = 0; j4 < 16; j4 += 4){
    float4 a = *(const float4*)(query + base + j4);
    qv[j4]=a.x; qv[j4+1]=a.y; qv[j4+2]=a.z; qv[j4+3]=a.w;
    a = *(const float4*)(key + base + j4);
    kv[j4]=a.x; kv[j4+1]=a.y; kv[j4+2]=a.z; kv[j4+3]=a.w;
    a = *(const float4*)(value + base + j4);
    vv[j4]=a.x; vv[j4+1]=a.y; vv[j4+2]=a.z; vv[j4+3]=a.w;
  }
  const float* dsp = dsb + n*C_ + h*D_;
  #pragma unroll
  for (int j = 0; j < 16; j++){ float d = dsp[j]; qv[j] += d; kv[j] += d; vv[j] += d; }
  __syncthreads();   // weights staged

  float qhr[16], khr[16], vhr[16];
  #pragma unroll
  for (int j = 0; j < 16; j++){
    float aq = 0.f, ak = 0.f, av = 0.f;
    #pragma unroll
    for (int i = 0; i < 16; i++){
      aq += qv[i] * wq[i][j];
      ak += kv[i] * wk[i][j];
      av += vv[i] * wv[i][j];
    }
    qhr[j] = aq; khr[j] = ak; vhr[j] = av;
  }
  #pragma unroll
  for (int j = 0; j < 16; j++){ qh[n][j] = qhr[j]; kh[n][j] = khr[j]; vh[n][j] = vhr[j]; }
  __syncthreads();

  // pass 1: thread = column k; online max/sum over q (softmax over axis=1 = q)
  float m = -1e30f, s = 0.f;
  for (int q = 0; q < N_; q++){
    float d = 0.f;
    #pragma unroll
    for (int j = 0; j < 16; j++) d += qh[q][j] * khr[j];
    d *= 0.125f;                       // 1/sqrt(C), C=64
    float mn = fmaxf(m, d);
    s = s * __expf(m - mn) + __expf(d - mn);
    m = mn;
  }
  mArr[n] = m;
  invArr[n] = 1.f / s;
  __syncthreads();

  // pass 2: thread = row q; O[q] = sum_k a[q,k] * vh[k]
  float o[16];
  #pragma unroll
  for (int j = 0; j < 16; j++) o[j] = 0.f;
  for (int k = 0; k < N_; k++){
    float d = 0.f;
    #pragma unroll
    for (int j = 0; j < 16; j++) d += qhr[j] * kh[k][j];
    float p = __expf(d * 0.125f - mArr[k]) * invArr[k];
    #pragma unroll
    for (int j = 0; j < 16; j++) o[j] += p * vh[k][j];
  }
  float* op = o_ws + base;
  #pragma unroll
  for (int j4 = 0; j4 < 16; j4 += 4)
    *(float4*)(op + j4) = make_float4(o[j4], o[j4+1], o[j4+2], o[j4+3]);
}

// ---------------- fused epilogue: fc -> LN1 -> FFN -> LN2 -> gate ; 8 tokens/block ----------------
__global__ __launch_bounds__(512)
void k_final(const float* __restrict__ query, const float* __restrict__ dsb,
             const float* __restrict__ o_ws, const float* __restrict__ xg_ws,
             const float* __restrict__ Wfc, const float* __restrict__ bfc,
             const float* __restrict__ ln1g, const float* __restrict__ ln1b,
             const float* __restrict__ ln2g, const float* __restrict__ ln2b,
             const float* __restrict__ Wff1, const float* __restrict__ bff1,
             const float* __restrict__ Wff2, const float* __restrict__ bff2,
             const float* __restrict__ Wfs, const float* __restrict__ bfs,
             const float* __restrict__ Wfg, const float* __restrict__ bfg,
             float* __restrict__ out)
{
  __shared__ float xs[8][C_];
  __shared__ float xgs[8][C_];
  __shared__ float ffs[8][4*C_];
  const int tid = threadIdx.x;
  const int w = tid >> 6, c = tid & 63;
  const size_t token = (size_t)blockIdx.x * 8 + w;       // (b*N+n)*T + t
  const int n = (int)((token / T_) & (N_-1));
  const size_t base = token * C_ + c;

  float qt = query[base] + dsb[n*C_ + c];
  xs[w][c] = o_ws[base];
  __syncthreads();

  float acc = bfc[c];
  for (int i = 0; i < C_; i++) acc += xs[w][i] * Wfc[i*C_ + c];
  float x1 = acc + qt;

  float mu = wsum64(x1) * (1.f/64.f);
  float d1 = x1 - mu;
  float var = wsum64(d1*d1) * (1.f/64.f);
  float ms = d1 * rsqrtf(var + 1e-5f) * ln1g[c] + ln1b[c];

  __syncthreads();
  xs[w][c] = ms;
  __syncthreads();

  #pragma unroll
  for (int rr = 0; rr < 4; rr++){
    int cc = rr*64 + c;
    float a = bff1[cc];
    for (int i = 0; i < C_; i++) a += xs[w][i] * Wff1[i*(4*C_) + cc];
    ffs[w][cc] = a > 0.f ? a : 0.f;
  }
  __syncthreads();

  float a2 = bff2[c];
  for (int k = 0; k < 4*C_; k++) a2 += ffs[w][k] * Wff2[k*C_ + c];
  float x2 = a2 + ms;

  float mu2 = wsum64(x2) * (1.f/64.f);
  float d2 = x2 - mu2;
  float var2 = wsum64(d2*d2) * (1.f/64.f);
  float us = d2 * rsqrtf(var2 + 1e-5f) * ln2g[c] + ln2b[c];

  __syncthreads();
  xs[w][c] = us;
  xgs[w][c] = xg_ws[base];
  __syncthreads();

  float ga = bfs[c] + bfg[c];
  for (int i = 0; i < C_; i++)
    ga += xs[w][i] * Wfs[i*C_ + c] + xgs[w][i] * Wfg[i*C_ + c];
  float gg = 1.f / (1.f + __expf(-ga));
  float res = gg * us + (1.f - gg) * xgs[w][c];
  out[base] = res;
}

extern "C" void kernel_launch(void* const* d_in, const int* in_sizes, int n_in,
                              void* d_out, int out_size, void* d_ws, size_t ws_size,
                              hipStream_t stream)
{
  (void)in_sizes; (void)n_in; (void)out_size; (void)ws_size;
  const float* query = (const float*)d_in[0];
  const float* key   = (const float*)d_in[1];
  const float* value = (const float*)d_in[2];
  // d_in[3] = edge_attr (unused by the reference forward)
  const float* DSm   = (const float*)d_in[4];
  const float* Wemb  = (const float*)d_in[5];
  const float* bemb  = (const float*)d_in[6];
  const float* Wq    = (const float*)d_in[7];
  const float* Wk    = (const float*)d_in[8];
  const float* Wv    = (const float*)d_in[9];
  const float* Wfc   = (const float*)d_in[10];
  const float* bfc   = (const float*)d_in[11];
  const float* ln1g  = (const float*)d_in[12];
  const float* ln1b  = (const float*)d_in[13];
  const float* ln2g  = (const float*)d_in[14];
  const float* ln2b  = (const float*)d_in[15];
  const float* Wff1  = (const float*)d_in[16];
  const float* bff1  = (const float*)d_in[17];
  const float* Wff2  = (const float*)d_in[18];
  const float* bff2  = (const float*)d_in[19];
  const float* g1W   = (const float*)d_in[20];
  const float* g1as  = (const float*)d_in[21];
  const float* g1ad  = (const float*)d_in[22];
  const float* g1b   = (const float*)d_in[23];
  const float* g2W   = (const float*)d_in[24];
  const float* g2as  = (const float*)d_in[25];
  const float* g2ad  = (const float*)d_in[26];
  const float* g2b   = (const float*)d_in[27];
  const float* jkW   = (const float*)d_in[28];
  const float* jkb   = (const float*)d_in[29];
  const float* Wfs   = (const float*)d_in[30];
  const float* bfs   = (const float*)d_in[31];
  const float* Wfg   = (const float*)d_in[32];
  const float* bfg   = (const float*)d_in[33];
  const int* ei      = (const int*)d_in[34];
  float* out = (float*)d_out;

  float* wf     = (float*)d_ws;
  float* dsb    = wf + DS_OFF;
  float* o_ws   = wf + O_OFF;
  float* xg_ws  = wf + XG_OFF;
  int*   indptr = (int*)(wf + INT_OFF);
  int*   srcs   = indptr + 260;

  k_csr<<<dim3(1), dim3(256), 0, stream>>>(ei, indptr, srcs);
  k_ds<<<dim3(N_), dim3(C_), 0, stream>>>(DSm, Wemb, bemb, dsb);
  k_gat<<<dim3(G_), dim3(512), 0, stream>>>(query,
      g1W, g1as, g1ad, g1b,
      g2W, g2as, g2ad, g2b,
      jkW, jkb, indptr, srcs, xg_ws);
  k_attn<<<dim3(B_*T_*H_), dim3(256), 0, stream>>>(query, key, value, Wq, Wk, Wv, dsb, o_ws);
  k_final<<<dim3(TOK_/8), dim3(512), 0, stream>>>(query, dsb, o_ws, xg_ws,
      Wfc, bfc, ln1g, ln1b, ln2g, ln2b,
      Wff1, bff1, Wff2, bff2,
      Wfs, bfs, Wfg, bfg, out);
}

// Round 3
// 447.995 us; speedup vs baseline: 1.6372x; 1.6372x over previous
//
#include <hip/hip_runtime.h>

typedef unsigned short u16;
typedef unsigned int u32;

#define B_ 4
#define N_ 256
#define T_ 36
#define C_ 64
#define H_ 4
#define D_ 16
#define CH_ 128
#define E_ 4096
#define G_ (B_*T_)
#define TOK_ (B_*N_*T_)

// workspace layout (float offsets)
#define DS_OFF  0
#define XG_OFF  (DS_OFF + N_*C_)
#define HA_OFF  (XG_OFF + TOK_*C_)          // bf16 h buffer A (conv outs) ; aliased by o_ws later
#define HB_OFF  (HA_OFF + G_*N_*CH_/2)      // bf16 buffer B (h1 / jk input)
#define HS_OFF  (HB_OFF + G_*N_*CH_/2)
#define HD_OFF  (HS_OFF + G_*N_)
#define INT_OFF (HD_OFF + G_*N_)

__device__ __forceinline__ float bf2f(u16 u){
  u32 x = ((u32)u) << 16;
  return __builtin_bit_cast(float, x);
}
__device__ __forceinline__ u16 f2bf(float f){
  u32 x = __builtin_bit_cast(u32, f);
  x += 0x7fffu + ((x >> 16) & 1u);
  return (u16)(x >> 16);
}
__device__ __forceinline__ void unpack8(uint4 u, float* f){
  f[0]=bf2f((u16)(u.x & 0xffffu)); f[1]=bf2f((u16)(u.x >> 16));
  f[2]=bf2f((u16)(u.y & 0xffffu)); f[3]=bf2f((u16)(u.y >> 16));
  f[4]=bf2f((u16)(u.z & 0xffffu)); f[5]=bf2f((u16)(u.z >> 16));
  f[6]=bf2f((u16)(u.w & 0xffffu)); f[7]=bf2f((u16)(u.w >> 16));
}
__device__ __forceinline__ uint4 pack8f(const float* f){
  uint4 u;
  u.x = (u32)f2bf(f[0]) | ((u32)f2bf(f[1]) << 16);
  u.y = (u32)f2bf(f[2]) | ((u32)f2bf(f[3]) << 16);
  u.z = (u32)f2bf(f[4]) | ((u32)f2bf(f[5]) << 16);
  u.w = (u32)f2bf(f[6]) | ((u32)f2bf(f[7]) << 16);
  return u;
}
__device__ __forceinline__ int rfl(int v){ return __builtin_amdgcn_readfirstlane(v); }

// ---------------- deterministic CSR: bucket by dst (atomic), stable-sort by edge id ----------------
__global__ void k_csr(const int* __restrict__ ei, int* __restrict__ indptr, int* __restrict__ srcs)
{
  __shared__ int srcL[E_];
  __shared__ int dstL[E_];
  __shared__ int tmp[E_];
  __shared__ int cnt[N_];
  __shared__ int base[N_+1];
  const int tid = threadIdx.x;   // 256
  for (int e = tid; e < E_; e += 256){ srcL[e] = ei[e]; dstL[e] = ei[E_ + e]; }
  cnt[tid] = 0;
  __syncthreads();
  for (int e = tid; e < E_; e += 256) atomicAdd(&cnt[dstL[e]], 1);
  __syncthreads();
  if (tid == 0){
    int run = 0;
    for (int i = 0; i < N_; i++){ base[i] = run; run += cnt[i]; }
    base[N_] = run;
  }
  __syncthreads();
  cnt[tid] = 0;
  __syncthreads();
  for (int e = tid; e < E_; e += 256){
    int d = dstL[e];
    int p = atomicAdd(&cnt[d], 1);
    tmp[base[d] + p] = e;
  }
  __syncthreads();
  {
    const int p0 = base[tid], p1 = base[tid] + cnt[tid];
    for (int i = p0 + 1; i < p1; i++){      // insertion sort by edge id -> stable/deterministic
      int v = tmp[i]; int j = i - 1;
      while (j >= p0 && tmp[j] > v){ tmp[j+1] = tmp[j]; j--; }
      tmp[j+1] = v;
    }
    for (int j = p0; j < p1; j++) srcs[j] = srcL[tmp[j]];
  }
  indptr[tid] = base[tid];
  if (tid == 0) indptr[N_] = base[N_];
}

// ---------------- ds = D_S @ W_emb + b_emb ----------------
__global__ void k_ds(const float* __restrict__ DSm, const float* __restrict__ Wemb,
                     const float* __restrict__ bemb, float* __restrict__ dsb)
{
  const int n = blockIdx.x, c = threadIdx.x;
  float acc = bemb[c];
  for (int m = 0; m < N_; m++) acc += DSm[n*N_ + m] * Wemb[m*C_ + c];
  dsb[n*C_ + c] = acc;
}

// ---------------- GAT conv1 linear: h = bf16(x @ W1), fused hs/hd ----------------
__global__ __launch_bounds__(256)
void k_lin1(const float* __restrict__ query, const float* __restrict__ W1,
            const float* __restrict__ as1, const float* __restrict__ ad1,
            u16* __restrict__ h, float* __restrict__ hs_ws, float* __restrict__ hd_ws)
{
  __shared__ float xs[64][65];
  __shared__ float red[2][4][64];
  const int bid = blockIdx.x;
  const int g = bid >> 2, n0 = (bid & 3) * 64;
  const int b = g / T_, t = g % T_;
  const int tid = threadIdx.x;

  // stage 64 rows x 64 cols of x (f32), coalesced
  {
    const size_t gb = (((size_t)b*N_ + n0)*T_ + t)*C_;
    #pragma unroll
    for (int it = 0; it < 4; it++){
      int idx = tid + 256*it;             // 0..1023
      int row = idx >> 4, c4 = (idx & 15) * 4;
      float4 v = *(const float4*)(query + gb + (size_t)row*(T_*C_) + c4);
      xs[row][c4+0] = v.x; xs[row][c4+1] = v.y; xs[row][c4+2] = v.z; xs[row][c4+3] = v.w;
    }
  }
  __syncthreads();

  const int r = tid & 63;
  const int cb = rfl(tid >> 6);
  const int ch0 = cb * 32;

  float acc[32];
  #pragma unroll
  for (int j = 0; j < 32; j++) acc[j] = 0.f;
  for (int k = 0; k < 64; k++){
    float xv = xs[r][k];
    const float* wrow = W1 + k*CH_ + ch0;   // scalar (uniform) loads
    #pragma unroll
    for (int j = 0; j < 32; j++) acc[j] += xv * wrow[j];
  }
  // fused hs/hd partials
  float hs = 0.f, hd = 0.f;
  #pragma unroll
  for (int j = 0; j < 32; j++){ hs += acc[j]*as1[ch0+j]; hd += acc[j]*ad1[ch0+j]; }
  red[0][cb][r] = hs; red[1][cb][r] = hd;

  // store h (bf16)
  u16* hp = h + ((size_t)(g*N_ + n0 + r))*CH_ + ch0;
  #pragma unroll
  for (int j8 = 0; j8 < 32; j8 += 8)
    *(uint4*)(hp + j8) = pack8f(&acc[j8]);

  __syncthreads();
  if (tid < 64){
    float a = red[0][0][tid]+red[0][1][tid]+red[0][2][tid]+red[0][3][tid];
    float d = red[1][0][tid]+red[1][1][tid]+red[1][2][tid]+red[1][3][tid];
    hs_ws[g*N_ + n0 + tid] = a;
    hd_ws[g*N_ + n0 + tid] = d;
  }
}

// ---------------- GAT conv2 linear: h2 = bf16(h1 @ W2), fused hs2/hd2 ----------------
__global__ __launch_bounds__(256)
void k_lin2(const u16* __restrict__ h1, const float* __restrict__ W2,
            const float* __restrict__ as2, const float* __restrict__ ad2,
            u16* __restrict__ h2, float* __restrict__ hs_ws, float* __restrict__ hd_ws)
{
  __shared__ float xs[64][129];
  __shared__ float red[2][4][64];
  const int bid = blockIdx.x;
  const int g = bid >> 2, n0 = (bid & 3) * 64;
  const int tid = threadIdx.x;

  // stage 64 rows x 128 cols of h1 (bf16 -> f32)
  {
    #pragma unroll
    for (int it = 0; it < 4; it++){
      int idx = tid + 256*it;             // 0..1023
      int row = idx >> 4, c8 = (idx & 15) * 8;
      uint4 u = *(const uint4*)(h1 + ((size_t)(g*N_ + n0 + row))*CH_ + c8);
      float v[8]; unpack8(u, v);
      #pragma unroll
      for (int i = 0; i < 8; i++) xs[row][c8+i] = v[i];
    }
  }
  __syncthreads();

  const int r = tid & 63;
  const int cb = rfl(tid >> 6);
  const int ch0 = cb * 32;

  float acc[32];
  #pragma unroll
  for (int j = 0; j < 32; j++) acc[j] = 0.f;
  for (int k = 0; k < 128; k++){
    float xv = xs[r][k];
    const float* wrow = W2 + k*CH_ + ch0;
    #pragma unroll
    for (int j = 0; j < 32; j++) acc[j] += xv * wrow[j];
  }
  float hs = 0.f, hd = 0.f;
  #pragma unroll
  for (int j = 0; j < 32; j++){ hs += acc[j]*as2[ch0+j]; hd += acc[j]*ad2[ch0+j]; }
  red[0][cb][r] = hs; red[1][cb][r] = hd;

  u16* hp = h2 + ((size_t)(g*N_ + n0 + r))*CH_ + ch0;
  #pragma unroll
  for (int j8 = 0; j8 < 32; j8 += 8)
    *(uint4*)(hp + j8) = pack8f(&acc[j8]);

  __syncthreads();
  if (tid < 64){
    float a = red[0][0][tid]+red[0][1][tid]+red[0][2][tid]+red[0][3][tid];
    float d = red[1][0][tid]+red[1][1][tid]+red[1][2][tid]+red[1][3][tid];
    hs_ws[g*N_ + n0 + tid] = a;
    hd_ws[g*N_ + n0 + tid] = d;
  }
}

// ---------------- GAT aggregation (+softmax in-block). layer2: jk max fused ----------------
__global__ __launch_bounds__(256)
void k_agg(const u16* __restrict__ hin, const float* __restrict__ hs_ws, const float* __restrict__ hd_ws,
           const int* __restrict__ indptr, const int* __restrict__ srcs,
           const float* __restrict__ bias, u16* __restrict__ hout, int layer2)
{
  __shared__ int   srcs_l[E_];
  __shared__ float alpha_l[E_];
  __shared__ float hs_l[N_];
  const int bid = blockIdx.x;
  const int g = bid >> 2, n0 = (bid & 3) * 64;
  const int tid = threadIdx.x;

  const int p00 = indptr[n0];
  const int pend = indptr[n0 + 64];
  const int cntE = pend - p00;
  for (int i = tid; i < cntE; i += 256) srcs_l[i] = srcs[p00 + i];
  hs_l[tid] = hs_ws[g*N_ + tid];
  __syncthreads();

  if (tid < 64){
    const int dst = n0 + tid;
    const int p0 = indptr[dst] - p00, p1 = indptr[dst+1] - p00;
    const float hdn = hd_ws[g*N_ + dst];
    for (int j = p0; j < p1; j++){
      float e = hs_l[srcs_l[j]] + hdn;
      alpha_l[j] = e > 0.f ? e : 0.2f * e;
    }
    float m = -1e30f;
    for (int j = p0; j < p1; j++) m = fmaxf(m, alpha_l[j]);
    float s = 0.f;
    for (int j = p0; j < p1; j++){
      float w = __expf(alpha_l[j] - m);
      alpha_l[j] = w; s += w;
    }
    float inv = 1.f / (s + 1e-16f);
    for (int j = p0; j < p1; j++) alpha_l[j] *= inv;
  }
  __syncthreads();

  const int r = tid & 63;
  const int cb = rfl(tid >> 6);
  const int ch0 = cb * 32;
  const int dst = n0 + r;
  const int p0 = indptr[dst] - p00, p1 = indptr[dst+1] - p00;

  float acc[32];
  #pragma unroll
  for (int j = 0; j < 32; j++) acc[j] = 0.f;
  for (int j = p0; j < p1; j++){
    float a = alpha_l[j];
    int s = srcs_l[j];
    const uint4* hp = (const uint4*)(hin + ((size_t)(g*N_ + s))*CH_ + ch0);
    #pragma unroll
    for (int q = 0; q < 4; q++){
      float hv[8]; unpack8(hp[q], hv);
      #pragma unroll
      for (int i = 0; i < 8; i++) acc[q*8+i] += a * hv[i];
    }
  }
  float o[32];
  #pragma unroll
  for (int j = 0; j < 32; j++){
    float v = acc[j] + bias[ch0+j];
    o[j] = v > 0.f ? v : 0.f;
  }
  u16* op = hout + ((size_t)(g*N_ + dst))*CH_ + ch0;
  if (layer2){
    #pragma unroll
    for (int j8 = 0; j8 < 32; j8 += 8){
      float h1v[8]; unpack8(*(const uint4*)(op + j8), h1v);
      #pragma unroll
      for (int i = 0; i < 8; i++) o[j8+i] = fmaxf(h1v[i], o[j8+i]);
    }
  }
  #pragma unroll
  for (int j8 = 0; j8 < 32; j8 += 8)
    *(uint4*)(op + j8) = pack8f(&o[j8]);
}

// ---------------- jk linear: xg(time-reversed) = jk @ jkW + jkb ----------------
__global__ __launch_bounds__(256)
void k_jk(const u16* __restrict__ jkin, const float* __restrict__ jkW, const float* __restrict__ jkb,
          float* __restrict__ xg)
{
  __shared__ float xs[64][129];
  const int bid = blockIdx.x;
  const int g = bid >> 2, n0 = (bid & 3) * 64;
  const int b = g / T_, t = g % T_;
  const int tid = threadIdx.x;

  {
    #pragma unroll
    for (int it = 0; it < 4; it++){
      int idx = tid + 256*it;
      int row = idx >> 4, c8 = (idx & 15) * 8;
      uint4 u = *(const uint4*)(jkin + ((size_t)(g*N_ + n0 + row))*CH_ + c8);
      float v[8]; unpack8(u, v);
      #pragma unroll
      for (int i = 0; i < 8; i++) xs[row][c8+i] = v[i];
    }
  }
  __syncthreads();

  const int r = tid & 63;
  const int cb = rfl(tid >> 6);
  const int o0 = cb * 16;

  float acc[16];
  #pragma unroll
  for (int j = 0; j < 16; j++) acc[j] = 0.f;
  for (int k = 0; k < 128; k++){
    float xv = xs[r][k];
    const float* wrow = jkW + k*C_ + o0;
    #pragma unroll
    for (int j = 0; j < 16; j++) acc[j] += xv * wrow[j];
  }
  float* op = xg + ((((size_t)b*N_ + n0 + r)*T_) + (T_-1-t))*C_ + o0;
  #pragma unroll
  for (int j4 = 0; j4 < 16; j4 += 4){
    float4 v = make_float4(acc[j4]+jkb[o0+j4], acc[j4+1]+jkb[o0+j4+1],
                           acc[j4+2]+jkb[o0+j4+2], acc[j4+3]+jkb[o0+j4+3]);
    *(float4*)(op + j4) = v;
  }
}

// ---------------- attention: one block per (b,t,h); softmax over the q axis ----------------
#define QP_ 20
__global__ __launch_bounds__(256, 2)
void k_attn(const float* __restrict__ query, const float* __restrict__ key, const float* __restrict__ value,
            const float* __restrict__ Wq, const float* __restrict__ Wk, const float* __restrict__ Wv,
            const float* __restrict__ dsb, float* __restrict__ o_ws)
{
  __shared__ float qh[N_][QP_];
  __shared__ float kh[N_][QP_];
  __shared__ float vh[N_][QP_];
  __shared__ float mArr[N_];
  __shared__ float invArr[N_];
  __shared__ float wq[16][16], wk[16][16], wv[16][16];

  const int bx = blockIdx.x;
  const int b = bx / (T_*H_);
  const int r = bx % (T_*H_);
  const int t = r / H_;
  const int h = r % H_;
  const int n = threadIdx.x;

  wq[n >> 4][n & 15] = Wq[n];
  wk[n >> 4][n & 15] = Wk[n];
  wv[n >> 4][n & 15] = Wv[n];

  const size_t base = ((((size_t)b*N_ + n)*T_) + t)*C_ + h*D_;
  float qv[16], kv[16], vv[16];
  #pragma unroll
  for (int j4 = 0; j4 < 16; j4 += 4){
    float4 a = *(const float4*)(query + base + j4);
    qv[j4]=a.x; qv[j4+1]=a.y; qv[j4+2]=a.z; qv[j4+3]=a.w;
    a = *(const float4*)(key + base + j4);
    kv[j4]=a.x; kv[j4+1]=a.y; kv[j4+2]=a.z; kv[j4+3]=a.w;
    a = *(const float4*)(value + base + j4);
    vv[j4]=a.x; vv[j4+1]=a.y; vv[j4+2]=a.z; vv[j4+3]=a.w;
  }
  const float* dsp = dsb + n*C_ + h*D_;
  #pragma unroll
  for (int j = 0; j < 16; j++){ float d = dsp[j]; qv[j] += d; kv[j] += d; vv[j] += d; }
  __syncthreads();   // weights staged

  float qhr[16], khr[16], vhr[16];
  #pragma unroll
  for (int j = 0; j < 16; j++){
    float aq = 0.f, ak = 0.f, av = 0.f;
    #pragma unroll
    for (int i = 0; i < 16; i++){
      aq += qv[i] * wq[i][j];
      ak += kv[i] * wk[i][j];
      av += vv[i] * wv[i][j];
    }
    qhr[j] = aq; khr[j] = ak; vhr[j] = av;
  }
  #pragma unroll
  for (int j = 0; j < 16; j++){ qh[n][j] = qhr[j]; kh[n][j] = khr[j]; vh[n][j] = vhr[j]; }
  __syncthreads();

  // pass 1: thread = column k; online max/sum over q (softmax over axis=1 = q)
  float m = -1e30f, s = 0.f;
  for (int q = 0; q < N_; q++){
    float d = 0.f;
    #pragma unroll
    for (int j = 0; j < 16; j++) d += qh[q][j] * khr[j];
    d *= 0.125f;
    float mn = fmaxf(m, d);
    s = s * __expf(m - mn) + __expf(d - mn);
    m = mn;
  }
  mArr[n] = m;
  invArr[n] = 1.f / s;
  __syncthreads();

  // pass 2: thread = row q
  float o[16];
  #pragma unroll
  for (int j = 0; j < 16; j++) o[j] = 0.f;
  for (int k = 0; k < N_; k++){
    float d = 0.f;
    #pragma unroll
    for (int j = 0; j < 16; j++) d += qhr[j] * kh[k][j];
    float p = __expf(d * 0.125f - mArr[k]) * invArr[k];
    #pragma unroll
    for (int j = 0; j < 16; j++) o[j] += p * vh[k][j];
  }
  float* op = o_ws + base;
  #pragma unroll
  for (int j4 = 0; j4 < 16; j4 += 4)
    *(float4*)(op + j4) = make_float4(o[j4], o[j4+1], o[j4+2], o[j4+3]);
}

// ---------------- fused epilogue, transposed: lane=token, wave=channel-half ----------------
// 64 tokens/block, 128 threads. Weights via wave-uniform scalar loads.
__global__ __launch_bounds__(128)
void k_final(const float* __restrict__ query, const float* __restrict__ dsb,
             const float* __restrict__ o_ws, const float* __restrict__ xg_ws,
             const float* __restrict__ Wfc, const float* __restrict__ bfc,
             const float* __restrict__ ln1g, const float* __restrict__ ln1b,
             const float* __restrict__ ln2g, const float* __restrict__ ln2b,
             const float* __restrict__ Wff1, const float* __restrict__ bff1,
             const float* __restrict__ Wff2, const float* __restrict__ bff2,
             const float* __restrict__ Wfs, const float* __restrict__ bfs,
             const float* __restrict__ Wfg, const float* __restrict__ bfg,
             float* __restrict__ out)
{
  __shared__ float smA[64*66];   // o_t -> ex[2][64][33] -> us_t
  __shared__ float smB[64*66];   // qd_t -> ms_t -> out_t
  __shared__ float smC[64*66];   // xg_t
  __shared__ float lnx[2][64];

  const int tid = threadIdx.x;
  const int token0 = blockIdx.x * 64;
  const int half = rfl(tid >> 6);      // wave id = channel half (wave-uniform)
  const int tok = tid & 63;
  const int c0 = half * 32;

  // stage o, q+ds, xg transposed [ch][tok]
  #pragma unroll
  for (int it = 0; it < 8; it++){
    int idx = tid + 128*it;             // 0..1023
    int tk = idx >> 4, c4 = (idx & 15) * 4;
    int gtok = token0 + tk;
    int n = (gtok / T_) & (N_-1);
    float4 ov = *(const float4*)(o_ws + (size_t)gtok*C_ + c4);
    float4 qv = *(const float4*)(query + (size_t)gtok*C_ + c4);
    float4 dv = *(const float4*)(dsb + n*C_ + c4);
    float4 xv = *(const float4*)(xg_ws + (size_t)gtok*C_ + c4);
    smA[(c4+0)*66+tk] = ov.x; smA[(c4+1)*66+tk] = ov.y; smA[(c4+2)*66+tk] = ov.z; smA[(c4+3)*66+tk] = ov.w;
    smB[(c4+0)*66+tk] = qv.x+dv.x; smB[(c4+1)*66+tk] = qv.y+dv.y; smB[(c4+2)*66+tk] = qv.z+dv.z; smB[(c4+3)*66+tk] = qv.w+dv.w;
    smC[(c4+0)*66+tk] = xv.x; smC[(c4+1)*66+tk] = xv.y; smC[(c4+2)*66+tk] = xv.z; smC[(c4+3)*66+tk] = xv.w;
  }
  __syncthreads();

  // fc: x1 = o @ Wfc + bfc + (q+ds)
  float acc[32];
  #pragma unroll
  for (int j = 0; j < 32; j++) acc[j] = 0.f;
  for (int i = 0; i < C_; i++){
    float ov = smA[i*66 + tok];
    const float* wrow = Wfc + i*C_ + c0;
    #pragma unroll
    for (int j = 0; j < 32; j++) acc[j] += ov * wrow[j];
  }
  float x1[32];
  #pragma unroll
  for (int j = 0; j < 32; j++) x1[j] = acc[j] + bfc[c0+j] + smB[(c0+j)*66 + tok];

  // LN1
  float s1 = 0.f;
  #pragma unroll
  for (int j = 0; j < 32; j++) s1 += x1[j];
  lnx[half][tok] = s1;
  __syncthreads();
  float mu = (lnx[0][tok] + lnx[1][tok]) * (1.f/64.f);
  __syncthreads();
  float v1 = 0.f;
  #pragma unroll
  for (int j = 0; j < 32; j++){ float d = x1[j]-mu; v1 += d*d; }
  lnx[half][tok] = v1;
  __syncthreads();
  float var = (lnx[0][tok] + lnx[1][tok]) * (1.f/64.f);
  float rstd = rsqrtf(var + 1e-5f);
  float ms[32];
  #pragma unroll
  for (int j = 0; j < 32; j++) ms[j] = (x1[j]-mu)*rstd*ln1g[c0+j] + ln1b[c0+j];
  __syncthreads();                       // lnx consumed
  #pragma unroll
  for (int j = 0; j < 32; j++) smB[(c0+j)*66 + tok] = ms[j];   // ms_t (qd dead)
  __syncthreads();

  // FFN: hidden chunked 4x32 (static reg indexing); part[] = ff2 partials for ALL 64 out-ch
  float part[64];
  #pragma unroll
  for (int c = 0; c < 64; c++) part[c] = 0.f;
  for (int ch = 0; ch < 4; ch++){
    float fch[32];
    #pragma unroll
    for (int kk = 0; kk < 32; kk++) fch[kk] = 0.f;
    const int kbase = half*128 + ch*32;
    for (int i = 0; i < C_; i++){
      float msv = smB[i*66 + tok];
      const float* wrow = Wff1 + i*(4*C_) + kbase;
      #pragma unroll
      for (int kk = 0; kk < 32; kk++) fch[kk] += msv * wrow[kk];
    }
    #pragma unroll
    for (int kk = 0; kk < 32; kk++){
      float v = fch[kk] + bff1[kbase+kk];
      fch[kk] = v > 0.f ? v : 0.f;
    }
    #pragma unroll
    for (int kk = 0; kk < 32; kk++){
      float fv = fch[kk];
      const float* wrow = Wff2 + (kbase+kk)*C_;
      #pragma unroll
      for (int c = 0; c < 64; c++) part[c] += fv * wrow[c];
    }
  }
  // exchange the other half's partial channels via smA (dead after fc; syncs since)
  {
    const int other = (1-half)*32;
    #pragma unroll
    for (int j = 0; j < 32; j++) smA[(half*64 + tok)*33 + j] = part[other + j];
  }
  __syncthreads();
  float x2[32];
  #pragma unroll
  for (int j = 0; j < 32; j++)
    x2[j] = part[c0+j] + smA[((1-half)*64 + tok)*33 + j] + bff2[c0+j] + ms[j];

  // LN2
  float s2 = 0.f;
  #pragma unroll
  for (int j = 0; j < 32; j++) s2 += x2[j];
  __syncthreads();
  lnx[half][tok] = s2;
  __syncthreads();
  float mu2 = (lnx[0][tok] + lnx[1][tok]) * (1.f/64.f);
  __syncthreads();
  float v2 = 0.f;
  #pragma unroll
  for (int j = 0; j < 32; j++){ float d = x2[j]-mu2; v2 += d*d; }
  lnx[half][tok] = v2;
  __syncthreads();
  float var2 = (lnx[0][tok] + lnx[1][tok]) * (1.f/64.f);
  float rstd2 = rsqrtf(var2 + 1e-5f);
  float us[32];
  #pragma unroll
  for (int j = 0; j < 32; j++) us[j] = (x2[j]-mu2)*rstd2*ln2g[c0+j] + ln2b[c0+j];
  __syncthreads();                       // ex-region + lnx consumed
  #pragma unroll
  for (int j = 0; j < 32; j++) smA[(c0+j)*66 + tok] = us[j];   // us_t
  __syncthreads();

  // gate: ga = us @ Wfs + xg @ Wfg + bfs + bfg
  float ga[32];
  #pragma unroll
  for (int j = 0; j < 32; j++) ga[j] = 0.f;
  for (int i = 0; i < C_; i++){
    float uv = smA[i*66 + tok];
    float xv = smC[i*66 + tok];
    const float* wsr = Wfs + i*C_ + c0;
    const float* wgr = Wfg + i*C_ + c0;
    #pragma unroll
    for (int j = 0; j < 32; j++) ga[j] += uv*wsr[j] + xv*wgr[j];
  }
  float res[32];
  #pragma unroll
  for (int j = 0; j < 32; j++){
    float a = ga[j] + bfs[c0+j] + bfg[c0+j];
    float gg = 1.f / (1.f + __expf(-a));
    float xgv = smC[(c0+j)*66 + tok];
    res[j] = gg*us[j] + (1.f-gg)*xgv;
  }
  // out transpose via smB (ms_t dead)
  #pragma unroll
  for (int j = 0; j < 32; j++) smB[(c0+j)*66 + tok] = res[j];
  __syncthreads();
  #pragma unroll
  for (int it = 0; it < 8; it++){
    int idx = tid + 128*it;
    int tk = idx >> 4, c4 = (idx & 15) * 4;
    int gtok = token0 + tk;
    float4 v = make_float4(smB[(c4+0)*66+tk], smB[(c4+1)*66+tk],
                           smB[(c4+2)*66+tk], smB[(c4+3)*66+tk]);
    *(float4*)(out + (size_t)gtok*C_ + c4) = v;
  }
}

extern "C" void kernel_launch(void* const* d_in, const int* in_sizes, int n_in,
                              void* d_out, int out_size, void* d_ws, size_t ws_size,
                              hipStream_t stream)
{
  (void)in_sizes; (void)n_in; (void)out_size; (void)ws_size;
  const float* query = (const float*)d_in[0];
  const float* key   = (const float*)d_in[1];
  const float* value = (const float*)d_in[2];
  const float* DSm   = (const float*)d_in[4];
  const float* Wemb  = (const float*)d_in[5];
  const float* bemb  = (const float*)d_in[6];
  const float* Wq    = (const float*)d_in[7];
  const float* Wk    = (const float*)d_in[8];
  const float* Wv    = (const float*)d_in[9];
  const float* Wfc   = (const float*)d_in[10];
  const float* bfc   = (const float*)d_in[11];
  const float* ln1g  = (const float*)d_in[12];
  const float* ln1b  = (const float*)d_in[13];
  const float* ln2g  = (const float*)d_in[14];
  const float* ln2b  = (const float*)d_in[15];
  const float* Wff1  = (const float*)d_in[16];
  const float* bff1  = (const float*)d_in[17];
  const float* Wff2  = (const float*)d_in[18];
  const float* bff2  = (const float*)d_in[19];
  const float* g1W   = (const float*)d_in[20];
  const float* g1as  = (const float*)d_in[21];
  const float* g1ad  = (const float*)d_in[22];
  const float* g1b   = (const float*)d_in[23];
  const float* g2W   = (const float*)d_in[24];
  const float* g2as  = (const float*)d_in[25];
  const float* g2ad  = (const float*)d_in[26];
  const float* g2b   = (const float*)d_in[27];
  const float* jkW   = (const float*)d_in[28];
  const float* jkb   = (const float*)d_in[29];
  const float* Wfs   = (const float*)d_in[30];
  const float* bfs   = (const float*)d_in[31];
  const float* Wfg   = (const float*)d_in[32];
  const float* bfg   = (const float*)d_in[33];
  const int* ei      = (const int*)d_in[34];
  float* out = (float*)d_out;

  float* wf     = (float*)d_ws;
  float* dsb    = wf + DS_OFF;
  float* xg_ws  = wf + XG_OFF;
  u16*   hA     = (u16*)(wf + HA_OFF);     // conv outputs (both layers)
  u16*   hB     = (u16*)(wf + HB_OFF);     // h1 / jk input
  float* o_ws   = wf + HA_OFF;             // aliases hA (dead before k_attn)
  float* hs_ws  = wf + HS_OFF;
  float* hd_ws  = wf + HD_OFF;
  int*   indptr = (int*)(wf + INT_OFF);
  int*   srcs   = indptr + 260;

  k_csr<<<dim3(1), dim3(256), 0, stream>>>(ei, indptr, srcs);
  k_ds<<<dim3(N_), dim3(C_), 0, stream>>>(DSm, Wemb, bemb, dsb);
  k_lin1<<<dim3(G_*4), dim3(256), 0, stream>>>(query, g1W, g1as, g1ad, hA, hs_ws, hd_ws);
  k_agg <<<dim3(G_*4), dim3(256), 0, stream>>>(hA, hs_ws, hd_ws, indptr, srcs, g1b, hB, 0);
  k_lin2<<<dim3(G_*4), dim3(256), 0, stream>>>(hB, g2W, g2as, g2ad, hA, hs_ws, hd_ws);
  k_agg <<<dim3(G_*4), dim3(256), 0, stream>>>(hA, hs_ws, hd_ws, indptr, srcs, g2b, hB, 1);
  k_jk  <<<dim3(G_*4), dim3(256), 0, stream>>>(hB, jkW, jkb, xg_ws);
  k_attn<<<dim3(B_*T_*H_), dim3(256), 0, stream>>>(query, key, value, Wq, Wk, Wv, dsb, o_ws);
  k_final<<<dim3(TOK_/64), dim3(128), 0, stream>>>(query, dsb, o_ws, xg_ws,
      Wfc, bfc, ln1g, ln1b, ln2g, ln2b,
      Wff1, bff1, Wff2, bff2,
      Wfs, bfs, Wfg, bfg, out);
}

// Round 4
// 405.547 us; speedup vs baseline: 1.8085x; 1.1047x over previous
//
#include <hip/hip_runtime.h>

typedef unsigned short u16;
typedef unsigned int u32;

#define B_ 4
#define N_ 256
#define T_ 36
#define C_ 64
#define H_ 4
#define D_ 16
#define CH_ 128
#define E_ 4096
#define G_ (B_*T_)
#define TOK_ (B_*N_*T_)

// workspace layout (float offsets)
#define DS_OFF  0
#define XG_OFF  (DS_OFF + N_*C_)
#define HA_OFF  (XG_OFF + TOK_*C_)          // bf16 h buffer A (conv outs) ; aliased by o_ws later
#define HB_OFF  (HA_OFF + G_*N_*CH_/2)      // bf16 buffer B (h1 / jk input)
#define HS_OFF  (HB_OFF + G_*N_*CH_/2)
#define HD_OFF  (HS_OFF + G_*N_)
#define INT_OFF (HD_OFF + G_*N_)

__device__ __forceinline__ float bf2f(u16 u){
  u32 x = ((u32)u) << 16;
  return __builtin_bit_cast(float, x);
}
__device__ __forceinline__ u16 f2bf(float f){
  u32 x = __builtin_bit_cast(u32, f);
  x += 0x7fffu + ((x >> 16) & 1u);
  return (u16)(x >> 16);
}
__device__ __forceinline__ void unpack8(uint4 u, float* f){
  f[0]=bf2f((u16)(u.x & 0xffffu)); f[1]=bf2f((u16)(u.x >> 16));
  f[2]=bf2f((u16)(u.y & 0xffffu)); f[3]=bf2f((u16)(u.y >> 16));
  f[4]=bf2f((u16)(u.z & 0xffffu)); f[5]=bf2f((u16)(u.z >> 16));
  f[6]=bf2f((u16)(u.w & 0xffffu)); f[7]=bf2f((u16)(u.w >> 16));
}
__device__ __forceinline__ uint4 pack8f(const float* f){
  uint4 u;
  u.x = (u32)f2bf(f[0]) | ((u32)f2bf(f[1]) << 16);
  u.y = (u32)f2bf(f[2]) | ((u32)f2bf(f[3]) << 16);
  u.z = (u32)f2bf(f[4]) | ((u32)f2bf(f[5]) << 16);
  u.w = (u32)f2bf(f[6]) | ((u32)f2bf(f[7]) << 16);
  return u;
}
__device__ __forceinline__ int rfl(int v){ return __builtin_amdgcn_readfirstlane(v); }

// ---------------- deterministic CSR: bucket by dst (atomic), stable-sort by edge id ----------------
__global__ void k_csr(const int* __restrict__ ei, int* __restrict__ indptr, int* __restrict__ srcs)
{
  __shared__ int srcL[E_];
  __shared__ int dstL[E_];
  __shared__ int tmp[E_];
  __shared__ int cnt[N_];
  __shared__ int base[N_+1];
  const int tid = threadIdx.x;   // 256
  for (int e = tid; e < E_; e += 256){ srcL[e] = ei[e]; dstL[e] = ei[E_ + e]; }
  cnt[tid] = 0;
  __syncthreads();
  for (int e = tid; e < E_; e += 256) atomicAdd(&cnt[dstL[e]], 1);
  __syncthreads();
  if (tid == 0){
    int run = 0;
    for (int i = 0; i < N_; i++){ base[i] = run; run += cnt[i]; }
    base[N_] = run;
  }
  __syncthreads();
  cnt[tid] = 0;
  __syncthreads();
  for (int e = tid; e < E_; e += 256){
    int d = dstL[e];
    int p = atomicAdd(&cnt[d], 1);
    tmp[base[d] + p] = e;
  }
  __syncthreads();
  {
    const int p0 = base[tid], p1 = base[tid] + cnt[tid];
    for (int i = p0 + 1; i < p1; i++){      // insertion sort by edge id -> stable/deterministic
      int v = tmp[i]; int j = i - 1;
      while (j >= p0 && tmp[j] > v){ tmp[j+1] = tmp[j]; j--; }
      tmp[j+1] = v;
    }
    for (int j = p0; j < p1; j++) srcs[j] = srcL[tmp[j]];
  }
  indptr[tid] = base[tid];
  if (tid == 0) indptr[N_] = base[N_];
}

// ---------------- ds = D_S @ W_emb + b_emb ----------------
__global__ void k_ds(const float* __restrict__ DSm, const float* __restrict__ Wemb,
                     const float* __restrict__ bemb, float* __restrict__ dsb)
{
  const int n = blockIdx.x, c = threadIdx.x;
  float acc = bemb[c];
  for (int m = 0; m < N_; m++) acc += DSm[n*N_ + m] * Wemb[m*C_ + c];
  dsb[n*C_ + c] = acc;
}

// ---------------- GAT conv1 linear: h = bf16(x @ W1), fused hs/hd ----------------
__global__ __launch_bounds__(256)
void k_lin1(const float* __restrict__ query, const float* __restrict__ W1,
            const float* __restrict__ as1, const float* __restrict__ ad1,
            u16* __restrict__ h, float* __restrict__ hs_ws, float* __restrict__ hd_ws)
{
  __shared__ float xs[64][65];
  __shared__ float red[2][4][64];
  const int bid = blockIdx.x;
  const int g = bid >> 2, n0 = (bid & 3) * 64;
  const int b = g / T_, t = g % T_;
  const int tid = threadIdx.x;

  {
    const size_t gb = (((size_t)b*N_ + n0)*T_ + t)*C_;
    #pragma unroll
    for (int it = 0; it < 4; it++){
      int idx = tid + 256*it;
      int row = idx >> 4, c4 = (idx & 15) * 4;
      float4 v = *(const float4*)(query + gb + (size_t)row*(T_*C_) + c4);
      xs[row][c4+0] = v.x; xs[row][c4+1] = v.y; xs[row][c4+2] = v.z; xs[row][c4+3] = v.w;
    }
  }
  __syncthreads();

  const int r = tid & 63;
  const int cb = rfl(tid >> 6);
  const int ch0 = cb * 32;

  float acc[32];
  #pragma unroll
  for (int j = 0; j < 32; j++) acc[j] = 0.f;
  for (int k = 0; k < 64; k++){
    float xv = xs[r][k];
    const float* wrow = W1 + k*CH_ + ch0;   // scalar (uniform) loads
    #pragma unroll
    for (int j = 0; j < 32; j++) acc[j] += xv * wrow[j];
  }
  float hs = 0.f, hd = 0.f;
  #pragma unroll
  for (int j = 0; j < 32; j++){ hs += acc[j]*as1[ch0+j]; hd += acc[j]*ad1[ch0+j]; }
  red[0][cb][r] = hs; red[1][cb][r] = hd;

  u16* hp = h + ((size_t)(g*N_ + n0 + r))*CH_ + ch0;
  #pragma unroll
  for (int j8 = 0; j8 < 32; j8 += 8)
    *(uint4*)(hp + j8) = pack8f(&acc[j8]);

  __syncthreads();
  if (tid < 64){
    float a = red[0][0][tid]+red[0][1][tid]+red[0][2][tid]+red[0][3][tid];
    float d = red[1][0][tid]+red[1][1][tid]+red[1][2][tid]+red[1][3][tid];
    hs_ws[g*N_ + n0 + tid] = a;
    hd_ws[g*N_ + n0 + tid] = d;
  }
}

// ---------------- GAT conv2 linear: h2 = bf16(h1 @ W2), fused hs2/hd2 ----------------
__global__ __launch_bounds__(256)
void k_lin2(const u16* __restrict__ h1, const float* __restrict__ W2,
            const float* __restrict__ as2, const float* __restrict__ ad2,
            u16* __restrict__ h2, float* __restrict__ hs_ws, float* __restrict__ hd_ws)
{
  __shared__ float xs[64][129];
  __shared__ float red[2][4][64];
  const int bid = blockIdx.x;
  const int g = bid >> 2, n0 = (bid & 3) * 64;
  const int tid = threadIdx.x;

  {
    #pragma unroll
    for (int it = 0; it < 4; it++){
      int idx = tid + 256*it;
      int row = idx >> 4, c8 = (idx & 15) * 8;
      uint4 u = *(const uint4*)(h1 + ((size_t)(g*N_ + n0 + row))*CH_ + c8);
      float v[8]; unpack8(u, v);
      #pragma unroll
      for (int i = 0; i < 8; i++) xs[row][c8+i] = v[i];
    }
  }
  __syncthreads();

  const int r = tid & 63;
  const int cb = rfl(tid >> 6);
  const int ch0 = cb * 32;

  float acc[32];
  #pragma unroll
  for (int j = 0; j < 32; j++) acc[j] = 0.f;
  for (int k = 0; k < 128; k++){
    float xv = xs[r][k];
    const float* wrow = W2 + k*CH_ + ch0;
    #pragma unroll
    for (int j = 0; j < 32; j++) acc[j] += xv * wrow[j];
  }
  float hs = 0.f, hd = 0.f;
  #pragma unroll
  for (int j = 0; j < 32; j++){ hs += acc[j]*as2[ch0+j]; hd += acc[j]*ad2[ch0+j]; }
  red[0][cb][r] = hs; red[1][cb][r] = hd;

  u16* hp = h2 + ((size_t)(g*N_ + n0 + r))*CH_ + ch0;
  #pragma unroll
  for (int j8 = 0; j8 < 32; j8 += 8)
    *(uint4*)(hp + j8) = pack8f(&acc[j8]);

  __syncthreads();
  if (tid < 64){
    float a = red[0][0][tid]+red[0][1][tid]+red[0][2][tid]+red[0][3][tid];
    float d = red[1][0][tid]+red[1][1][tid]+red[1][2][tid]+red[1][3][tid];
    hs_ws[g*N_ + n0 + tid] = a;
    hd_ws[g*N_ + n0 + tid] = d;
  }
}

// ---------------- GAT aggregation (+softmax in-block). layer2: jk max fused ----------------
__global__ __launch_bounds__(256)
void k_agg(const u16* __restrict__ hin, const float* __restrict__ hs_ws, const float* __restrict__ hd_ws,
           const int* __restrict__ indptr, const int* __restrict__ srcs,
           const float* __restrict__ bias, u16* __restrict__ hout, int layer2)
{
  __shared__ int   srcs_l[E_];
  __shared__ float alpha_l[E_];
  __shared__ float hs_l[N_];
  const int bid = blockIdx.x;
  const int g = bid >> 2, n0 = (bid & 3) * 64;
  const int tid = threadIdx.x;

  const int p00 = indptr[n0];
  const int pend = indptr[n0 + 64];
  const int cntE = pend - p00;
  for (int i = tid; i < cntE; i += 256) srcs_l[i] = srcs[p00 + i];
  hs_l[tid] = hs_ws[g*N_ + tid];
  __syncthreads();

  if (tid < 64){
    const int dst = n0 + tid;
    const int p0 = indptr[dst] - p00, p1 = indptr[dst+1] - p00;
    const float hdn = hd_ws[g*N_ + dst];
    for (int j = p0; j < p1; j++){
      float e = hs_l[srcs_l[j]] + hdn;
      alpha_l[j] = e > 0.f ? e : 0.2f * e;
    }
    float m = -1e30f;
    for (int j = p0; j < p1; j++) m = fmaxf(m, alpha_l[j]);
    float s = 0.f;
    for (int j = p0; j < p1; j++){
      float w = __expf(alpha_l[j] - m);
      alpha_l[j] = w; s += w;
    }
    float inv = 1.f / (s + 1e-16f);
    for (int j = p0; j < p1; j++) alpha_l[j] *= inv;
  }
  __syncthreads();

  const int r = tid & 63;
  const int cb = rfl(tid >> 6);
  const int ch0 = cb * 32;
  const int dst = n0 + r;
  const int p0 = indptr[dst] - p00, p1 = indptr[dst+1] - p00;

  float acc[32];
  #pragma unroll
  for (int j = 0; j < 32; j++) acc[j] = 0.f;
  for (int j = p0; j < p1; j++){
    float a = alpha_l[j];
    int s = srcs_l[j];
    const uint4* hp = (const uint4*)(hin + ((size_t)(g*N_ + s))*CH_ + ch0);
    #pragma unroll
    for (int q = 0; q < 4; q++){
      float hv[8]; unpack8(hp[q], hv);
      #pragma unroll
      for (int i = 0; i < 8; i++) acc[q*8+i] += a * hv[i];
    }
  }
  float o[32];
  #pragma unroll
  for (int j = 0; j < 32; j++){
    float v = acc[j] + bias[ch0+j];
    o[j] = v > 0.f ? v : 0.f;
  }
  u16* op = hout + ((size_t)(g*N_ + dst))*CH_ + ch0;
  if (layer2){
    #pragma unroll
    for (int j8 = 0; j8 < 32; j8 += 8){
      float h1v[8]; unpack8(*(const uint4*)(op + j8), h1v);
      #pragma unroll
      for (int i = 0; i < 8; i++) o[j8+i] = fmaxf(h1v[i], o[j8+i]);
    }
  }
  #pragma unroll
  for (int j8 = 0; j8 < 32; j8 += 8)
    *(uint4*)(op + j8) = pack8f(&o[j8]);
}

// ---------------- jk linear: xg(time-reversed) = jk @ jkW + jkb ----------------
__global__ __launch_bounds__(256)
void k_jk(const u16* __restrict__ jkin, const float* __restrict__ jkW, const float* __restrict__ jkb,
          float* __restrict__ xg)
{
  __shared__ float xs[64][129];
  const int bid = blockIdx.x;
  const int g = bid >> 2, n0 = (bid & 3) * 64;
  const int b = g / T_, t = g % T_;
  const int tid = threadIdx.x;

  {
    #pragma unroll
    for (int it = 0; it < 4; it++){
      int idx = tid + 256*it;
      int row = idx >> 4, c8 = (idx & 15) * 8;
      uint4 u = *(const uint4*)(jkin + ((size_t)(g*N_ + n0 + row))*CH_ + c8);
      float v[8]; unpack8(u, v);
      #pragma unroll
      for (int i = 0; i < 8; i++) xs[row][c8+i] = v[i];
    }
  }
  __syncthreads();

  const int r = tid & 63;
  const int cb = rfl(tid >> 6);
  const int o0 = cb * 16;

  float acc[16];
  #pragma unroll
  for (int j = 0; j < 16; j++) acc[j] = 0.f;
  for (int k = 0; k < 128; k++){
    float xv = xs[r][k];
    const float* wrow = jkW + k*C_ + o0;
    #pragma unroll
    for (int j = 0; j < 16; j++) acc[j] += xv * wrow[j];
  }
  float* op = xg + ((((size_t)b*N_ + n0 + r)*T_) + (T_-1-t))*C_ + o0;
  #pragma unroll
  for (int j4 = 0; j4 < 16; j4 += 4){
    float4 v = make_float4(acc[j4]+jkb[o0+j4], acc[j4+1]+jkb[o0+j4+1],
                           acc[j4+2]+jkb[o0+j4+2], acc[j4+3]+jkb[o0+j4+3]);
    *(float4*)(op + j4) = v;
  }
}

// ---------------- attention: one block per (b,t,h); softmax over the q axis ----------------
#define QP_ 20
__global__ __launch_bounds__(256, 2)
void k_attn(const float* __restrict__ query, const float* __restrict__ key, const float* __restrict__ value,
            const float* __restrict__ Wq, const float* __restrict__ Wk, const float* __restrict__ Wv,
            const float* __restrict__ dsb, float* __restrict__ o_ws)
{
  __shared__ float qh[N_][QP_];
  __shared__ float kh[N_][QP_];
  __shared__ float vh[N_][QP_];
  __shared__ float mArr[N_];
  __shared__ float invArr[N_];
  __shared__ float wq[16][16], wk[16][16], wv[16][16];

  const int bx = blockIdx.x;
  const int b = bx / (T_*H_);
  const int r = bx % (T_*H_);
  const int t = r / H_;
  const int h = r % H_;
  const int n = threadIdx.x;

  wq[n >> 4][n & 15] = Wq[n];
  wk[n >> 4][n & 15] = Wk[n];
  wv[n >> 4][n & 15] = Wv[n];

  const size_t base = ((((size_t)b*N_ + n)*T_) + t)*C_ + h*D_;
  float qv[16], kv[16], vv[16];
  #pragma unroll
  for (int j4 = 0; j4 < 16; j4 += 4){
    float4 a = *(const float4*)(query + base + j4);
    qv[j4]=a.x; qv[j4+1]=a.y; qv[j4+2]=a.z; qv[j4+3]=a.w;
    a = *(const float4*)(key + base + j4);
    kv[j4]=a.x; kv[j4+1]=a.y; kv[j4+2]=a.z; kv[j4+3]=a.w;
    a = *(const float4*)(value + base + j4);
    vv[j4]=a.x; vv[j4+1]=a.y; vv[j4+2]=a.z; vv[j4+3]=a.w;
  }
  const float* dsp = dsb + n*C_ + h*D_;
  #pragma unroll
  for (int j = 0; j < 16; j++){ float d = dsp[j]; qv[j] += d; kv[j] += d; vv[j] += d; }
  __syncthreads();

  float qhr[16], khr[16], vhr[16];
  #pragma unroll
  for (int j = 0; j < 16; j++){
    float aq = 0.f, ak = 0.f, av = 0.f;
    #pragma unroll
    for (int i = 0; i < 16; i++){
      aq += qv[i] * wq[i][j];
      ak += kv[i] * wk[i][j];
      av += vv[i] * wv[i][j];
    }
    qhr[j] = aq; khr[j] = ak; vhr[j] = av;
  }
  #pragma unroll
  for (int j = 0; j < 16; j++){ qh[n][j] = qhr[j]; kh[n][j] = khr[j]; vh[n][j] = vhr[j]; }
  __syncthreads();

  float m = -1e30f, s = 0.f;
  for (int q = 0; q < N_; q++){
    float d = 0.f;
    #pragma unroll
    for (int j = 0; j < 16; j++) d += qh[q][j] * khr[j];
    d *= 0.125f;
    float mn = fmaxf(m, d);
    s = s * __expf(m - mn) + __expf(d - mn);
    m = mn;
  }
  mArr[n] = m;
  invArr[n] = 1.f / s;
  __syncthreads();

  float o[16];
  #pragma unroll
  for (int j = 0; j < 16; j++) o[j] = 0.f;
  for (int k = 0; k < N_; k++){
    float d = 0.f;
    #pragma unroll
    for (int j = 0; j < 16; j++) d += qhr[j] * kh[k][j];
    float p = __expf(d * 0.125f - mArr[k]) * invArr[k];
    #pragma unroll
    for (int j = 0; j < 16; j++) o[j] += p * vh[k][j];
  }
  float* op = o_ws + base;
  #pragma unroll
  for (int j4 = 0; j4 < 16; j4 += 4)
    *(float4*)(op + j4) = make_float4(o[j4], o[j4+1], o[j4+2], o[j4+3]);
}

// ---------------- fused epilogue, transposed: lane=token, wave=16-ch quarter ----------------
// 64 tokens/block, 256 threads (4 waves). Weights wave-uniform scalar loads. No big per-thread arrays.
__global__ __launch_bounds__(256)
void k_final(const float* __restrict__ query, const float* __restrict__ dsb,
             const float* __restrict__ o_ws, const float* __restrict__ xg_ws,
             const float* __restrict__ Wfc, const float* __restrict__ bfc,
             const float* __restrict__ ln1g, const float* __restrict__ ln1b,
             const float* __restrict__ ln2g, const float* __restrict__ ln2b,
             const float* __restrict__ Wff1, const float* __restrict__ bff1,
             const float* __restrict__ Wff2, const float* __restrict__ bff2,
             const float* __restrict__ Wfs, const float* __restrict__ bfs,
             const float* __restrict__ Wfg, const float* __restrict__ bfg,
             float* __restrict__ out)
{
  __shared__ float smA[64*66];    // o_t -> us_t
  __shared__ float smB[64*66];    // qd_t -> ms_t -> out_t
  __shared__ float smH[128*66];   // ff1 hidden chunks -> xg_t
  __shared__ float lnxA[4][64];
  __shared__ float lnxB[4][64];

  const int tid = threadIdx.x;
  const int token0 = blockIdx.x * 64;
  const int w = rfl(tid >> 6);         // wave id (wave-uniform)
  const int tok = tid & 63;
  const int c0 = w * 16;               // output channel quarter

  // stage o, q+ds transposed [ch][tok]
  #pragma unroll
  for (int it = 0; it < 4; it++){
    int idx = tid + 256*it;             // 0..1023
    int tk = idx >> 4, c4 = (idx & 15) * 4;
    int gtok = token0 + tk;
    int n = (gtok / T_) & (N_-1);
    float4 ov = *(const float4*)(o_ws + (size_t)gtok*C_ + c4);
    float4 qv = *(const float4*)(query + (size_t)gtok*C_ + c4);
    float4 dv = *(const float4*)(dsb + n*C_ + c4);
    smA[(c4+0)*66+tk] = ov.x; smA[(c4+1)*66+tk] = ov.y; smA[(c4+2)*66+tk] = ov.z; smA[(c4+3)*66+tk] = ov.w;
    smB[(c4+0)*66+tk] = qv.x+dv.x; smB[(c4+1)*66+tk] = qv.y+dv.y; smB[(c4+2)*66+tk] = qv.z+dv.z; smB[(c4+3)*66+tk] = qv.w+dv.w;
  }
  __syncthreads();

  // fc: x1 = o @ Wfc + bfc + (q+ds), this wave's 16 channels
  float x1[16];
  #pragma unroll
  for (int j = 0; j < 16; j++) x1[j] = 0.f;
  for (int i = 0; i < C_; i++){
    float ov = smA[i*66 + tok];
    const float* wrow = Wfc + i*C_ + c0;
    #pragma unroll
    for (int j = 0; j < 16; j++) x1[j] += ov * wrow[j];
  }
  #pragma unroll
  for (int j = 0; j < 16; j++) x1[j] += bfc[c0+j] + smB[(c0+j)*66 + tok];

  // LN1 (cross-wave via lnxA/lnxB)
  float s1 = 0.f;
  #pragma unroll
  for (int j = 0; j < 16; j++) s1 += x1[j];
  lnxA[w][tok] = s1;
  __syncthreads();
  float mu = (lnxA[0][tok]+lnxA[1][tok]+lnxA[2][tok]+lnxA[3][tok]) * (1.f/64.f);
  float v1 = 0.f;
  #pragma unroll
  for (int j = 0; j < 16; j++){ float d = x1[j]-mu; v1 += d*d; }
  lnxB[w][tok] = v1;
  __syncthreads();
  float var = (lnxB[0][tok]+lnxB[1][tok]+lnxB[2][tok]+lnxB[3][tok]) * (1.f/64.f);
  float rstd = rsqrtf(var + 1e-5f);
  float ms[16];
  #pragma unroll
  for (int j = 0; j < 16; j++) ms[j] = (x1[j]-mu)*rstd*ln1g[c0+j] + ln1b[c0+j];
  __syncthreads();                 // all qd reads done; safe to overwrite smB
  #pragma unroll
  for (int j = 0; j < 16; j++) smB[(c0+j)*66 + tok] = ms[j];
  __syncthreads();

  // FFN: wave w owns hidden [w*64, w*64+64) in two 32-chunks via smH; part[16] only
  float part[16];
  #pragma unroll
  for (int j = 0; j < 16; j++) part[j] = 0.f;
  #pragma unroll
  for (int ch = 0; ch < 2; ch++){
    float fch[32];
    #pragma unroll
    for (int kk = 0; kk < 32; kk++) fch[kk] = 0.f;
    const int kbase = w*64 + ch*32;
    for (int i = 0; i < C_; i++){
      float msv = smB[i*66 + tok];
      const float* wrow = Wff1 + i*(4*C_) + kbase;
      #pragma unroll
      for (int kk = 0; kk < 32; kk++) fch[kk] += msv * wrow[kk];
    }
    #pragma unroll
    for (int kk = 0; kk < 32; kk++){
      float v = fch[kk] + bff1[kbase+kk];
      fch[kk] = v > 0.f ? v : 0.f;
    }
    if (ch) __syncthreads();       // chunk-1 write must wait for chunk-0 reads
    #pragma unroll
    for (int kk = 0; kk < 32; kk++) smH[(w*32+kk)*66 + tok] = fch[kk];
    __syncthreads();
    // ff2 partial over these 128 hidden (4 waves x 32)
    #pragma unroll
    for (int wq = 0; wq < 4; wq++){
      #pragma unroll 8
      for (int kk = 0; kk < 32; kk++){
        int k = wq*64 + ch*32 + kk;           // global hidden index
        float hv = smH[(wq*32+kk)*66 + tok];
        const float* wrow = Wff2 + k*C_ + c0;
        #pragma unroll
        for (int j = 0; j < 16; j++) part[j] += hv * wrow[j];
      }
    }
  }
  float x2[16];
  #pragma unroll
  for (int j = 0; j < 16; j++) x2[j] = part[j] + bff2[c0+j] + ms[j];

  // LN2
  float s2 = 0.f;
  #pragma unroll
  for (int j = 0; j < 16; j++) s2 += x2[j];
  __syncthreads();                 // chunk-1 ff2 reads done before lnxA reuse is fine; also guards smH
  lnxA[w][tok] = s2;
  __syncthreads();
  float mu2 = (lnxA[0][tok]+lnxA[1][tok]+lnxA[2][tok]+lnxA[3][tok]) * (1.f/64.f);
  float v2 = 0.f;
  #pragma unroll
  for (int j = 0; j < 16; j++){ float d = x2[j]-mu2; v2 += d*d; }
  lnxB[w][tok] = v2;
  __syncthreads();
  float var2 = (lnxB[0][tok]+lnxB[1][tok]+lnxB[2][tok]+lnxB[3][tok]) * (1.f/64.f);
  float rstd2 = rsqrtf(var2 + 1e-5f);
  float us[16];
  #pragma unroll
  for (int j = 0; j < 16; j++) us[j] = (x2[j]-mu2)*rstd2*ln2g[c0+j] + ln2b[c0+j];

  // write us_t -> smA (o dead); stage xg_t -> smH rows 0..63 (hidden dead)
  #pragma unroll
  for (int j = 0; j < 16; j++) smA[(c0+j)*66 + tok] = us[j];
  #pragma unroll
  for (int it = 0; it < 4; it++){
    int idx = tid + 256*it;
    int tk = idx >> 4, c4 = (idx & 15) * 4;
    int gtok = token0 + tk;
    float4 xv = *(const float4*)(xg_ws + (size_t)gtok*C_ + c4);
    smH[(c4+0)*66+tk] = xv.x; smH[(c4+1)*66+tk] = xv.y; smH[(c4+2)*66+tk] = xv.z; smH[(c4+3)*66+tk] = xv.w;
  }
  __syncthreads();

  // gate
  float ga[16];
  #pragma unroll
  for (int j = 0; j < 16; j++) ga[j] = 0.f;
  for (int i = 0; i < C_; i++){
    float uv = smA[i*66 + tok];
    float xv = smH[i*66 + tok];
    const float* wsr = Wfs + i*C_ + c0;
    const float* wgr = Wfg + i*C_ + c0;
    #pragma unroll
    for (int j = 0; j < 16; j++) ga[j] += uv*wsr[j] + xv*wgr[j];
  }
  float res[16];
  #pragma unroll
  for (int j = 0; j < 16; j++){
    float a = ga[j] + bfs[c0+j] + bfg[c0+j];
    float gg = 1.f / (1.f + __expf(-a));
    float xgv = smH[(c0+j)*66 + tok];
    res[j] = gg*us[j] + (1.f-gg)*xgv;
  }
  __syncthreads();                 // ms reads (ffn) long done; reuse smB for out
  #pragma unroll
  for (int j = 0; j < 16; j++) smB[(c0+j)*66 + tok] = res[j];
  __syncthreads();
  #pragma unroll
  for (int it = 0; it < 4; it++){
    int idx = tid + 256*it;
    int tk = idx >> 4, c4 = (idx & 15) * 4;
    int gtok = token0 + tk;
    float4 v = make_float4(smB[(c4+0)*66+tk], smB[(c4+1)*66+tk],
                           smB[(c4+2)*66+tk], smB[(c4+3)*66+tk]);
    *(float4*)(out + (size_t)gtok*C_ + c4) = v;
  }
}

extern "C" void kernel_launch(void* const* d_in, const int* in_sizes, int n_in,
                              void* d_out, int out_size, void* d_ws, size_t ws_size,
                              hipStream_t stream)
{
  (void)in_sizes; (void)n_in; (void)out_size; (void)ws_size;
  const float* query = (const float*)d_in[0];
  const float* key   = (const float*)d_in[1];
  const float* value = (const float*)d_in[2];
  const float* DSm   = (const float*)d_in[4];
  const float* Wemb  = (const float*)d_in[5];
  const float* bemb  = (const float*)d_in[6];
  const float* Wq    = (const float*)d_in[7];
  const float* Wk    = (const float*)d_in[8];
  const float* Wv    = (const float*)d_in[9];
  const float* Wfc   = (const float*)d_in[10];
  const float* bfc   = (const float*)d_in[11];
  const float* ln1g  = (const float*)d_in[12];
  const float* ln1b  = (const float*)d_in[13];
  const float* ln2g  = (const float*)d_in[14];
  const float* ln2b  = (const float*)d_in[15];
  const float* Wff1  = (const float*)d_in[16];
  const float* bff1  = (const float*)d_in[17];
  const float* Wff2  = (const float*)d_in[18];
  const float* bff2  = (const float*)d_in[19];
  const float* g1W   = (const float*)d_in[20];
  const float* g1as  = (const float*)d_in[21];
  const float* g1ad  = (const float*)d_in[22];
  const float* g1b   = (const float*)d_in[23];
  const float* g2W   = (const float*)d_in[24];
  const float* g2as  = (const float*)d_in[25];
  const float* g2ad  = (const float*)d_in[26];
  const float* g2b   = (const float*)d_in[27];
  const float* jkW   = (const float*)d_in[28];
  const float* jkb   = (const float*)d_in[29];
  const float* Wfs   = (const float*)d_in[30];
  const float* bfs   = (const float*)d_in[31];
  const float* Wfg   = (const float*)d_in[32];
  const float* bfg   = (const float*)d_in[33];
  const int* ei      = (const int*)d_in[34];
  float* out = (float*)d_out;

  float* wf     = (float*)d_ws;
  float* dsb    = wf + DS_OFF;
  float* xg_ws  = wf + XG_OFF;
  u16*   hA     = (u16*)(wf + HA_OFF);
  u16*   hB     = (u16*)(wf + HB_OFF);
  float* o_ws   = wf + HA_OFF;             // aliases hA (dead before k_attn)
  float* hs_ws  = wf + HS_OFF;
  float* hd_ws  = wf + HD_OFF;
  int*   indptr = (int*)(wf + INT_OFF);
  int*   srcs   = indptr + 260;

  k_csr<<<dim3(1), dim3(256), 0, stream>>>(ei, indptr, srcs);
  k_ds<<<dim3(N_), dim3(C_), 0, stream>>>(DSm, Wemb, bemb, dsb);
  k_lin1<<<dim3(G_*4), dim3(256), 0, stream>>>(query, g1W, g1as, g1ad, hA, hs_ws, hd_ws);
  k_agg <<<dim3(G_*4), dim3(256), 0, stream>>>(hA, hs_ws, hd_ws, indptr, srcs, g1b, hB, 0);
  k_lin2<<<dim3(G_*4), dim3(256), 0, stream>>>(hB, g2W, g2as, g2ad, hA, hs_ws, hd_ws);
  k_agg <<<dim3(G_*4), dim3(256), 0, stream>>>(hA, hs_ws, hd_ws, indptr, srcs, g2b, hB, 1);
  k_jk  <<<dim3(G_*4), dim3(256), 0, stream>>>(hB, jkW, jkb, xg_ws);
  k_attn<<<dim3(B_*T_*H_), dim3(256), 0, stream>>>(query, key, value, Wq, Wk, Wv, dsb, o_ws);
  k_final<<<dim3(TOK_/64), dim3(256), 0, stream>>>(query, dsb, o_ws, xg_ws,
      Wfc, bfc, ln1g, ln1b, ln2g, ln2b,
      Wff1, bff1, Wff2, bff2,
      Wfs, bfs, Wfg, bfg, out);
}